// Round 1
// baseline (378.246 us; speedup 1.0000x reference)
//
#include <hip/hip_runtime.h>
#include <stdint.h>

#define NB   8192
#define DIN  512
#define NH1  4096
#define NH2  4096
#define NA   64

typedef int v4i __attribute__((ext_vector_type(4)));

// ---- async global->LDS, 16B per lane (dest = wave-uniform base + lane*16) ----
__device__ __forceinline__ void gload16(const void* g, const void* l) {
    __builtin_amdgcn_global_load_lds(
        (const __attribute__((address_space(1))) void*)(uintptr_t)g,
        (__attribute__((address_space(3))) void*)(uint32_t)(uintptr_t)l,
        16, 0, 0);
}

// ---------------- converts ----------------
__global__ void cvt_i8(const float* __restrict__ in, signed char* __restrict__ out, int n4) {
    const int i = blockIdx.x * blockDim.x + threadIdx.x;
    if (i >= n4) return;
    const float4 v = ((const float4*)in)[i];
    char4 c;
    c.x = (signed char)__float2int_rn(v.x);
    c.y = (signed char)__float2int_rn(v.y);
    c.z = (signed char)__float2int_rn(v.z);
    c.w = (signed char)__float2int_rn(v.w);
    ((char4*)out)[i] = c;
}

// w_prob (64 x 4096 f32) -> wpT4[kg*64 + a] = char4{ wp[a][4kg..4kg+3] }
__global__ void build_wpT(const float* __restrict__ wp, char4* __restrict__ wpT4) {
    const int t = blockIdx.x * blockDim.x + threadIdx.x;   // 65536 threads
    const int a  = t & 63;
    const int kg = t >> 6;
    const float4 v = ((const float4*)wp)[a * (NH2 / 4) + kg];
    char4 c;
    c.x = (signed char)__float2int_rn(v.x);
    c.y = (signed char)__float2int_rn(v.y);
    c.z = (signed char)__float2int_rn(v.z);
    c.w = (signed char)__float2int_rn(v.w);
    wpT4[kg * 64 + a] = c;
}

// ---------------- i8 GEMM, C = A(MxK) * B(NxK)^T, tile 128x128, BK=64 ----------------
// EPI=1: h1q = clip(round(relu(round(M*acc+b)) / s), -128, 127) as int8
// EPI=2: h2  = relu(round(M*(acc+b)))  as uint16
template <int EPI>
__global__ __launch_bounds__(256)
void gemm_i8(const signed char* __restrict__ Ag,
             const signed char* __restrict__ Bg,
             int M, int N, int K,
             const float* __restrict__ bias,
             const float* __restrict__ Mscale,
             const float* __restrict__ qscale,
             void* __restrict__ outp)
{
    __shared__ __align__(16) signed char As[128 * 64];
    __shared__ __align__(16) signed char Bs[128 * 64];

    const int tid  = threadIdx.x;
    const int lane = tid & 63;
    const int wid  = tid >> 6;
    const int wr   = wid >> 1, wc = wid & 1;

    // XCD-aware bijective swizzle (grid divisible by 8)
    const int nwg = gridDim.x;
    const int bid = blockIdx.x;
    const int swzb = (bid & 7) * (nwg >> 3) + (bid >> 3);
    const int nbx = N >> 7;
    const int bx = swzb % nbx;
    const int by = swzb / nbx;
    const int bm0 = by << 7, bn0 = bx << 7;

    // ---- staging addresses: thread t stages 16B at phys chunk (row=t>>2, p=t&3),
    // holding logical chunk c = p ^ ((row>>1)&3)  (both-sides swizzle) ----
    const int srow = tid >> 2;
    const int clog = (tid & 3) ^ ((tid >> 3) & 3);
    const signed char* aSrc0 = Ag + (size_t)(bm0 + srow)      * K + clog * 16;
    const signed char* aSrc1 = Ag + (size_t)(bm0 + 64 + srow) * K + clog * 16;
    const signed char* bSrc0 = Bg + (size_t)(bn0 + srow)      * K + clog * 16;
    const signed char* bSrc1 = Bg + (size_t)(bn0 + 64 + srow) * K + clog * 16;
    const signed char* aDst0 = As + tid * 16;
    const signed char* aDst1 = As + 4096 + tid * 16;
    const signed char* bDst0 = Bs + tid * 16;
    const signed char* bDst1 = Bs + 4096 + tid * 16;

    // ---- ds_read addresses: lane wants row = base + (lane&15), k-chunk cg = lane>>4 ----
    const int r   = lane & 15;
    const int cg  = lane >> 4;
    const int csw = (cg ^ ((r >> 1) & 3)) * 16;
    const int aoff = (wr * 64 + r) * 64 + csw;
    const int boff = (wc * 64 + r) * 64 + csw;

    v4i acc[4][4] = {};

    for (int k0 = 0; k0 < K; k0 += 64) {
        gload16(aSrc0 + k0, aDst0);
        gload16(aSrc1 + k0, aDst1);
        gload16(bSrc0 + k0, bDst0);
        gload16(bSrc1 + k0, bDst1);
        __syncthreads();   // drains vmcnt -> LDS tile ready

        v4i af[4], bf[4];
        #pragma unroll
        for (int m = 0; m < 4; ++m) af[m] = *(const v4i*)(As + aoff + m * 1024);
        #pragma unroll
        for (int n = 0; n < 4; ++n) bf[n] = *(const v4i*)(Bs + boff + n * 1024);

        #pragma unroll
        for (int m = 0; m < 4; ++m)
            #pragma unroll
            for (int n = 0; n < 4; ++n)
                acc[m][n] = __builtin_amdgcn_mfma_i32_16x16x64_i8(af[m], bf[n], acc[m][n], 0, 0, 0);

        __syncthreads();   // protect LDS from next stage
    }

    // ---- epilogue: C/D layout col = lane&15, row = (lane>>4)*4 + j ----
    const int rowb = bm0 + wr * 64 + ((lane >> 4) << 2);
    const int colb = bn0 + wc * 64 + (lane & 15);

    if constexpr (EPI == 1) {
        const float Mv = Mscale[0];
        const float sv = qscale[0];
        signed char* out = (signed char*)outp;
        #pragma unroll
        for (int n = 0; n < 4; ++n) {
            const int col  = colb + n * 16;
            const int bint = __float2int_rn(bias[col]);
            #pragma unroll
            for (int m = 0; m < 4; ++m) {
                #pragma unroll
                for (int j = 0; j < 4; ++j) {
                    const int row  = rowb + m * 16 + j;
                    const int accv = acc[m][n][j] + bint;          // |acc1| <= 8.4M: f32-exact
                    float h = rintf(Mv * (float)accv);             // round(M1*acc), half-even
                    h = fmaxf(h, 0.0f);                            // relu
                    float q = rintf(h / sv);                       // quantize
                    q = fminf(fmaxf(q, -128.0f), 127.0f);
                    out[(size_t)row * N + col] = (signed char)(int)q;
                }
            }
        }
    } else {
        const float Mv = Mscale[0];
        unsigned short* out = (unsigned short*)outp;
        #pragma unroll
        for (int n = 0; n < 4; ++n) {
            const int col  = colb + n * 16;
            const int bint = __float2int_rn(bias[col]);
            #pragma unroll
            for (int m = 0; m < 4; ++m) {
                #pragma unroll
                for (int j = 0; j < 4; ++j) {
                    const int row  = rowb + m * 16 + j;
                    const int accv = acc[m][n][j] + bint;          // |acc2| <= 66.6M: use f64
                    double rr = rint((double)Mv * (double)accv);   // exact round(M2*acc)
                    rr = rr > 0.0 ? rr : 0.0;                      // relu; <= 65024 -> u16
                    out[(size_t)row * N + col] = (unsigned short)rr;
                }
            }
        }
    }
}

// ---------------- head: prob[r][a] = round(Mp * (sum_k h2[r][k]*wp[a][k] + bp[a])) ----------------
__global__ __launch_bounds__(256)
void head_k(const unsigned short* __restrict__ h2,
            const char4* __restrict__ wpT4,
            const float* __restrict__ bprob,
            const float* __restrict__ Mp,
            float* __restrict__ out)
{
    __shared__ __align__(16) char4 wlds[128 * 64];   // 32 KiB K-tile of w_prob^T
    const int tid  = threadIdx.x;
    const int lane = tid & 63;
    const int wid  = tid >> 6;
    const int r0   = blockIdx.x * 8 + wid * 2;       // 2 rows per wave

    int acc0 = 0, acc1 = 0;
    const unsigned short* p0 = h2 + (size_t)r0 * NH2;
    const unsigned short* p1 = p0 + NH2;

    for (int kt = 0; kt < NH2; kt += 512) {
        __syncthreads();                              // protect previous tile reads
        const int4* src = (const int4*)(wpT4 + (kt >> 2) * 64);
        int4* dst = (int4*)wlds;
        #pragma unroll
        for (int i = 0; i < 8; ++i)
            dst[tid + i * 256] = src[tid + i * 256];
        __syncthreads();

        #pragma unroll 4
        for (int kg = 0; kg < 128; ++kg) {
            const char4 w   = wlds[kg * 64 + lane];          // conflict-free: 64 consecutive dwords
            const ushort4 a = ((const ushort4*)(p0 + kt))[kg]; // wave-uniform broadcast
            const ushort4 b = ((const ushort4*)(p1 + kt))[kg];
            acc0 += (int)a.x * w.x + (int)a.y * w.y + (int)a.z * w.z + (int)a.w * w.w;
            acc1 += (int)b.x * w.x + (int)b.y * w.y + (int)b.z * w.z + (int)b.w * w.w;
        }
    }
    const int bint = __float2int_rn(bprob[lane]);
    const double mp = (double)Mp[0];
    out[(size_t)r0 * NA + lane]       = (float)rint(mp * (double)(acc0 + bint));
    out[(size_t)(r0 + 1) * NA + lane] = (float)rint(mp * (double)(acc1 + bint));
}

// ---------------- launcher ----------------
extern "C" void kernel_launch(void* const* d_in, const int* in_sizes, int n_in,
                              void* d_out, int out_size, void* d_ws, size_t ws_size,
                              hipStream_t stream) {
    const float* x  = (const float*)d_in[0];
    const float* w1 = (const float*)d_in[1];
    const float* b1 = (const float*)d_in[2];
    const float* w2 = (const float*)d_in[3];
    const float* b2 = (const float*)d_in[4];
    const float* wp = (const float*)d_in[7];
    const float* bp = (const float*)d_in[8];
    const float* M1 = (const float*)d_in[9];
    const float* M2 = (const float*)d_in[10];
    const float* Mp = (const float*)d_in[12];
    const float* s2 = (const float*)d_in[13];

    char* ws = (char*)d_ws;
    signed char*    x_i8  = (signed char*)(ws);                         // 4 MiB
    signed char*    w1_i8 = (signed char*)(ws + ((size_t)4  << 20));    // 2 MiB
    signed char*    w2_i8 = (signed char*)(ws + ((size_t)6  << 20));    // 16 MiB
    char4*          wpT4  = (char4*)      (ws + ((size_t)22 << 20));    // 256 KiB
    signed char*    h1q   = (signed char*)(ws + ((size_t)23 << 20));    // 32 MiB
    unsigned short* h2    = (unsigned short*)(ws + ((size_t)55 << 20)); // 64 MiB  (total 119 MiB)

    cvt_i8<<<dim3(4096),  dim3(256), 0, stream>>>(x,  x_i8,  NB  * DIN / 4);
    cvt_i8<<<dim3(2048),  dim3(256), 0, stream>>>(w1, w1_i8, NH1 * DIN / 4);
    cvt_i8<<<dim3(16384), dim3(256), 0, stream>>>(w2, w2_i8, NH2 * NH1 / 4);
    build_wpT<<<dim3(256), dim3(256), 0, stream>>>(wp, wpT4);

    // GEMM1: (8192x512) x (4096x512)^T -> h1q int8
    gemm_i8<1><<<dim3((NB / 128) * (NH1 / 128)), dim3(256), 0, stream>>>(
        x_i8, w1_i8, NB, NH1, DIN, b1, M1, s2, (void*)h1q);
    // GEMM2: (8192x4096) x (4096x4096)^T -> h2 uint16
    gemm_i8<2><<<dim3((NB / 128) * (NH2 / 128)), dim3(256), 0, stream>>>(
        h1q, w2_i8, NB, NH2, NH1, b2, M2, nullptr, (void*)h2);
    // head
    head_k<<<dim3(NB / 8), dim3(256), 0, stream>>>(h2, wpT4, bp, Mp, (float*)d_out);
}

// Round 2
// 349.106 us; speedup vs baseline: 1.0835x; 1.0835x over previous
//
#include <hip/hip_runtime.h>
#include <stdint.h>

#define NB   8192
#define DIN  512
#define NH1  4096
#define NH2  4096
#define NA   64

typedef int v4i __attribute__((ext_vector_type(4)));

// ---- async global->LDS, 16B per lane (dest = wave-uniform base + lane*16) ----
__device__ __forceinline__ void gload16(const void* g, const void* l) {
    __builtin_amdgcn_global_load_lds(
        (const __attribute__((address_space(1))) void*)(uintptr_t)g,
        (__attribute__((address_space(3))) void*)(uint32_t)(uintptr_t)l,
        16, 0, 0);
}

// ---------------- converts ----------------
__global__ void cvt_i8(const float* __restrict__ in, signed char* __restrict__ out, int n4) {
    const int i = blockIdx.x * blockDim.x + threadIdx.x;
    if (i >= n4) return;
    const float4 v = ((const float4*)in)[i];
    char4 c;
    c.x = (signed char)__float2int_rn(v.x);
    c.y = (signed char)__float2int_rn(v.y);
    c.z = (signed char)__float2int_rn(v.z);
    c.w = (signed char)__float2int_rn(v.w);
    ((char4*)out)[i] = c;
}

// w_prob (64 x 4096 f32) -> wpT4[kg*64 + a] = char4{ wp[a][4kg..4kg+3] }
__global__ void build_wpT(const float* __restrict__ wp, char4* __restrict__ wpT4) {
    const int t = blockIdx.x * blockDim.x + threadIdx.x;   // 65536 threads
    const int a  = t & 63;
    const int kg = t >> 6;
    const float4 v = ((const float4*)wp)[a * (NH2 / 4) + kg];
    char4 c;
    c.x = (signed char)__float2int_rn(v.x);
    c.y = (signed char)__float2int_rn(v.y);
    c.z = (signed char)__float2int_rn(v.z);
    c.w = (signed char)__float2int_rn(v.w);
    wpT4[kg * 64 + a] = c;
}

// ---------------- i8 GEMM, C = A(MxK) * B(NxK)^T ----------------
// 256x256 tile, BK=64, 8 waves (2x4), triple-buffered LDS, counted vmcnt.
// EPI=1: h1q = clip(round(relu(round(M*acc+b)) / s), -128, 127) as int8
// EPI=2: h2  = relu(round(M*(acc+b)))  as uint16
template <int EPI>
__global__ __launch_bounds__(512, 2)
void gemm_i8_8p(const signed char* __restrict__ Ag,
                const signed char* __restrict__ Bg,
                int M, int N, int K,
                const float* __restrict__ bias,
                const float* __restrict__ Mscale,
                const float* __restrict__ qscale,
                void* __restrict__ outp)
{
    // [buf][ A: 256x64 (16K) | B: 256x64 (16K) ]
    __shared__ __align__(16) signed char lds[3][32768];

    const int tid  = threadIdx.x;
    const int lane = tid & 63;
    const int wid  = tid >> 6;
    const int wm   = wid >> 2, wn = wid & 3;   // 2 x 4 wave grid

    // XCD-aware bijective swizzle (grid divisible by 8)
    const int nwg  = gridDim.x;
    const int bid  = blockIdx.x;
    const int swzb = (bid & 7) * (nwg >> 3) + (bid >> 3);
    const int nbx  = N >> 8;
    const int bx   = swzb % nbx;
    const int by   = swzb / nbx;
    const int bm0  = by << 8, bn0 = bx << 8;

    // staging: one set = 128 rows x 64 B = 8 KiB = 512 thr x 16 B.
    // thread t: phys (row=t>>2, chunk=t&3) holds logical chunk (t&3)^((t>>3)&3)
    const int srow  = tid >> 2;
    const int sclog = (tid & 3) ^ ((tid >> 3) & 3);
    const signed char* aS = Ag + (size_t)(bm0 + srow) * K + sclog * 16;
    const signed char* bS = Bg + (size_t)(bn0 + srow) * K + sclog * 16;
    const size_t rK = (size_t)128 * K;   // 128-row stride

    #define STAGE_A(bufp, koff) do { \
        gload16(aS + (koff),      &lds[bufp][0]    + tid * 16); \
        gload16(aS + rK + (koff), &lds[bufp][8192] + tid * 16); } while (0)
    #define STAGE_B(bufp, koff) do { \
        gload16(bS + (koff),      &lds[bufp][16384] + tid * 16); \
        gload16(bS + rK + (koff), &lds[bufp][24576] + tid * 16); } while (0)

    // ds_read: lane reads row (...+ lane&15), logical chunk lane>>4; swizzle indep. of m
    const int r    = lane & 15;
    const int lc   = lane >> 4;
    const int pc   = (lc ^ ((r >> 1) & 3)) * 16;
    const int aoff = wm * 8192 + r * 64 + pc;           // + m*1024
    const int boff = 16384 + wn * 4096 + r * 64 + pc;   // + n*1024

    const int nt = K >> 6;

    // prologue: stage tiles 0 and 1; wait tile 0, keep tile 1 in flight
    STAGE_A(0, 0); STAGE_B(0, 0);
    STAGE_A(1, 64); STAGE_B(1, 64);
    asm volatile("s_waitcnt vmcnt(4)" ::: "memory");
    __builtin_amdgcn_s_barrier();

    v4i acc[8][4] = {};
    int cur = 0, nxt = 2;

    for (int t = 0; t < nt; ++t) {
        const signed char* L = &lds[cur][0];
        const bool pf = (t + 2) < nt;
        const int ko = (t + 2) << 6;

        // ---- phase 0: reads + A-prefetch + MFMA m=0..3 ----
        v4i bf[4], af[4];
        #pragma unroll
        for (int n = 0; n < 4; ++n) bf[n] = *(const v4i*)(L + boff + n * 1024);
        #pragma unroll
        for (int m = 0; m < 4; ++m) af[m] = *(const v4i*)(L + aoff + m * 1024);
        if (pf) STAGE_A(nxt, ko);
        __builtin_amdgcn_s_barrier();
        __builtin_amdgcn_s_setprio(1);
        #pragma unroll
        for (int m = 0; m < 4; ++m)
            #pragma unroll
            for (int n = 0; n < 4; ++n)
                acc[m][n] = __builtin_amdgcn_mfma_i32_16x16x64_i8(af[m], bf[n], acc[m][n], 0, 0, 0);
        __builtin_amdgcn_s_setprio(0);
        __builtin_amdgcn_s_barrier();

        // ---- phase 1: reads (m=4..7) + B-prefetch + counted vmcnt + MFMA ----
        #pragma unroll
        for (int m = 0; m < 4; ++m) af[m] = *(const v4i*)(L + aoff + 4096 + m * 1024);
        if (pf) STAGE_B(nxt, ko);
        if (t + 1 < nt) {
            if (pf) asm volatile("s_waitcnt vmcnt(4)" ::: "memory");  // tile t+1 ready, t+2 in flight
            else    asm volatile("s_waitcnt vmcnt(0)" ::: "memory");  // final boundary only
        }
        __builtin_amdgcn_s_barrier();
        __builtin_amdgcn_s_setprio(1);
        #pragma unroll
        for (int m = 0; m < 4; ++m)
            #pragma unroll
            for (int n = 0; n < 4; ++n)
                acc[4 + m][n] = __builtin_amdgcn_mfma_i32_16x16x64_i8(af[m], bf[n], acc[4 + m][n], 0, 0, 0);
        __builtin_amdgcn_s_setprio(0);
        __builtin_amdgcn_s_barrier();

        cur = (cur == 2) ? 0 : cur + 1;
        nxt = (nxt == 2) ? 0 : nxt + 1;
    }
    #undef STAGE_A
    #undef STAGE_B

    // ---- epilogue: C/D layout col = lane&15, row = (lane>>4)*4 + j ----
    const int rowb = bm0 + wm * 128 + ((lane >> 4) << 2);
    const int colb = bn0 + wn * 64 + (lane & 15);

    if constexpr (EPI == 1) {
        const float Mv = Mscale[0];
        const float sv = qscale[0];
        signed char* out = (signed char*)outp;
        #pragma unroll
        for (int n = 0; n < 4; ++n) {
            const int col  = colb + n * 16;
            const int bint = __float2int_rn(bias[col]);
            #pragma unroll
            for (int m = 0; m < 8; ++m) {
                #pragma unroll
                for (int j = 0; j < 4; ++j) {
                    const int row  = rowb + m * 16 + j;
                    const int accv = acc[m][n][j] + bint;          // |acc1| <= 8.4M: f32-exact
                    float h = rintf(Mv * (float)accv);             // round(M1*acc), half-even
                    h = fmaxf(h, 0.0f);                            // relu
                    float q = rintf(h / sv);                       // quantize
                    q = fminf(fmaxf(q, -128.0f), 127.0f);
                    out[(size_t)row * N + col] = (signed char)(int)q;
                }
            }
        }
    } else {
        const float Mv = Mscale[0];
        unsigned short* out = (unsigned short*)outp;
        #pragma unroll
        for (int n = 0; n < 4; ++n) {
            const int col  = colb + n * 16;
            const int bint = __float2int_rn(bias[col]);
            #pragma unroll
            for (int m = 0; m < 8; ++m) {
                #pragma unroll
                for (int j = 0; j < 4; ++j) {
                    const int row  = rowb + m * 16 + j;
                    const int accv = acc[m][n][j] + bint;          // |acc2| <= 66.6M: use f64
                    double rr = rint((double)Mv * (double)accv);   // exact round(M2*acc)
                    rr = rr > 0.0 ? rr : 0.0;                      // relu; <= 65024 -> u16
                    out[(size_t)row * N + col] = (unsigned short)rr;
                }
            }
        }
    }
}

// ---------------- head: prob[r][a] = round(Mp * (sum_k h2[r][k]*wp[a][k] + bp[a])) ----------------
__global__ __launch_bounds__(256)
void head_k(const unsigned short* __restrict__ h2,
            const char4* __restrict__ wpT4,
            const float* __restrict__ bprob,
            const float* __restrict__ Mp,
            float* __restrict__ out)
{
    __shared__ __align__(16) char4 wlds[128 * 64];   // 32 KiB K-tile of w_prob^T
    const int tid  = threadIdx.x;
    const int lane = tid & 63;
    const int wid  = tid >> 6;
    const int r0   = blockIdx.x * 8 + wid * 2;       // 2 rows per wave

    int acc0 = 0, acc1 = 0;
    const unsigned short* p0 = h2 + (size_t)r0 * NH2;
    const unsigned short* p1 = p0 + NH2;

    for (int kt = 0; kt < NH2; kt += 512) {
        __syncthreads();                              // protect previous tile reads
        const int4* src = (const int4*)(wpT4 + (kt >> 2) * 64);
        int4* dst = (int4*)wlds;
        #pragma unroll
        for (int i = 0; i < 8; ++i)
            dst[tid + i * 256] = src[tid + i * 256];
        __syncthreads();

        #pragma unroll 4
        for (int kg = 0; kg < 128; ++kg) {
            const char4 w   = wlds[kg * 64 + lane];            // conflict-free
            const ushort4 a = ((const ushort4*)(p0 + kt))[kg]; // wave-uniform broadcast
            const ushort4 b = ((const ushort4*)(p1 + kt))[kg];
            acc0 += (int)a.x * w.x + (int)a.y * w.y + (int)a.z * w.z + (int)a.w * w.w;
            acc1 += (int)b.x * w.x + (int)b.y * w.y + (int)b.z * w.z + (int)b.w * w.w;
        }
    }
    const int bint = __float2int_rn(bprob[lane]);
    const double mp = (double)Mp[0];
    out[(size_t)r0 * NA + lane]       = (float)rint(mp * (double)(acc0 + bint));
    out[(size_t)(r0 + 1) * NA + lane] = (float)rint(mp * (double)(acc1 + bint));
}

// ---------------- launcher ----------------
extern "C" void kernel_launch(void* const* d_in, const int* in_sizes, int n_in,
                              void* d_out, int out_size, void* d_ws, size_t ws_size,
                              hipStream_t stream) {
    const float* x  = (const float*)d_in[0];
    const float* w1 = (const float*)d_in[1];
    const float* b1 = (const float*)d_in[2];
    const float* w2 = (const float*)d_in[3];
    const float* b2 = (const float*)d_in[4];
    const float* wp = (const float*)d_in[7];
    const float* bp = (const float*)d_in[8];
    const float* M1 = (const float*)d_in[9];
    const float* M2 = (const float*)d_in[10];
    const float* Mp = (const float*)d_in[12];
    const float* s2 = (const float*)d_in[13];

    char* ws = (char*)d_ws;
    signed char*    x_i8  = (signed char*)(ws);                         // 4 MiB
    signed char*    w1_i8 = (signed char*)(ws + ((size_t)4  << 20));    // 2 MiB
    signed char*    w2_i8 = (signed char*)(ws + ((size_t)6  << 20));    // 16 MiB
    char4*          wpT4  = (char4*)      (ws + ((size_t)22 << 20));    // 256 KiB
    signed char*    h1q   = (signed char*)(ws + ((size_t)23 << 20));    // 32 MiB
    unsigned short* h2    = (unsigned short*)(ws + ((size_t)55 << 20)); // 64 MiB  (total 119 MiB)

    cvt_i8<<<dim3(4096),  dim3(256), 0, stream>>>(x,  x_i8,  NB  * DIN / 4);
    cvt_i8<<<dim3(2048),  dim3(256), 0, stream>>>(w1, w1_i8, NH1 * DIN / 4);
    cvt_i8<<<dim3(16384), dim3(256), 0, stream>>>(w2, w2_i8, NH2 * NH1 / 4);
    build_wpT<<<dim3(256), dim3(256), 0, stream>>>(wp, wpT4);

    // GEMM1: (8192x512) x (4096x512)^T -> h1q int8
    gemm_i8_8p<1><<<dim3((NB / 256) * (NH1 / 256)), dim3(512), 0, stream>>>(
        x_i8, w1_i8, NB, NH1, DIN, b1, M1, s2, (void*)h1q);
    // GEMM2: (8192x4096) x (4096x4096)^T -> h2 uint16
    gemm_i8_8p<2><<<dim3((NB / 256) * (NH2 / 256)), dim3(512), 0, stream>>>(
        h1q, w2_i8, NB, NH2, NH1, b2, M2, nullptr, (void*)h2);
    // head
    head_k<<<dim3(NB / 8), dim3(256), 0, stream>>>(h2, wpT4, bp, Mp, (float*)d_out);
}

// Round 3
// 227.413 us; speedup vs baseline: 1.6633x; 1.5351x over previous
//
#include <hip/hip_runtime.h>
#include <stdint.h>

#define NB   8192
#define DIN  512
#define NH1  4096
#define NH2  4096
#define NA   64

typedef int v4i __attribute__((ext_vector_type(4)));

// ---- async global->LDS, 16B per lane (dest = wave-uniform base + lane*16) ----
__device__ __forceinline__ void gload16(const void* g, const void* l) {
    __builtin_amdgcn_global_load_lds(
        (const __attribute__((address_space(1))) void*)(uintptr_t)g,
        (__attribute__((address_space(3))) void*)(uint32_t)(uintptr_t)l,
        16, 0, 0);
}

// ---------------- converts ----------------
__global__ void cvt_i8(const float* __restrict__ in, signed char* __restrict__ out, int n4) {
    const int i = blockIdx.x * blockDim.x + threadIdx.x;
    if (i >= n4) return;
    const float4 v = ((const float4*)in)[i];
    char4 c;
    c.x = (signed char)__float2int_rn(v.x);
    c.y = (signed char)__float2int_rn(v.y);
    c.z = (signed char)__float2int_rn(v.z);
    c.w = (signed char)__float2int_rn(v.w);
    ((char4*)out)[i] = c;
}

// S[a] = sum_k round(wp[a][k])
__global__ void sum_wp(const float* __restrict__ wp, int* __restrict__ S) {
    __shared__ int red[256];
    const int a = blockIdx.x, t = threadIdx.x;
    int p = 0;
    for (int k = t; k < NH2; k += 256) p += __float2int_rn(wp[(size_t)a * NH2 + k]);
    red[t] = p; __syncthreads();
    for (int s = 128; s > 0; s >>= 1) { if (t < s) red[t] += red[t + s]; __syncthreads(); }
    if (t == 0) S[a] = red[0];
}

// ---------------- i8 GEMM, C = A(MxK) * B(NxK)^T ----------------
// 256x128 tile, BK=64, 8 waves (4Mx2N), triple-buffered LDS (72KB), 2 blocks/CU,
// counted vmcnt(3) (never 0 in steady state), LDS-staged coalesced epilogue.
// EPI=1: h1q  = clip(round(relu(round(M*acc+b))/s), -128,127)  i8  -> out0
// EPI=2: rr   = relu(round(M*(acc+b))); out0 = (rr&255)-128, out1 = (rr>>8)-128  (i8 planes)
template <int EPI>
__global__ __launch_bounds__(512, 4)
void gemm_i8_t3(const signed char* __restrict__ Ag,
                const signed char* __restrict__ Bg,
                int M, int N, int K,
                const float* __restrict__ bias,
                const float* __restrict__ Mscale,
                const float* __restrict__ qscale,
                signed char* __restrict__ out0,
                signed char* __restrict__ out1)
{
    // buf: [A 256x64 : 16384 | B 128x64 : 8192] = 24KB; x3 = 72KB
    __shared__ __align__(16) signed char lds[3][24576];

    const int tid  = threadIdx.x;
    const int lane = tid & 63;
    const int wid  = tid >> 6;
    const int wm   = wid >> 1, wn = wid & 1;     // 4 x 2 wave grid, 64x64 per wave

    // XCD-aware bijective swizzle (grid divisible by 8)
    const int nwg  = gridDim.x;
    const int bid  = blockIdx.x;
    const int swzb = (bid & 7) * (nwg >> 3) + (bid >> 3);
    const int nbx  = N >> 7;
    const int bx   = swzb % nbx;
    const int by   = swzb / nbx;
    const int bm0  = by << 8, bn0 = bx << 7;

    // staging: thread t -> phys (row=t>>2, chunk=t&3), logical chunk (t&3)^((t>>3)&3)
    const int srow  = tid >> 2;
    const int sclog = (tid & 3) ^ ((tid >> 3) & 3);
    const signed char* aS = Ag + (size_t)(bm0 + srow) * K + sclog * 16;
    const signed char* bS = Bg + (size_t)(bn0 + srow) * K + sclog * 16;
    const size_t rK = (size_t)128 * K;

    #define STAGE(bp, ko) do { \
        gload16(aS + (ko),      &lds[bp][0]     + tid * 16); \
        gload16(aS + rK + (ko), &lds[bp][8192]  + tid * 16); \
        gload16(bS + (ko),      &lds[bp][16384] + tid * 16); } while (0)

    // ds_read: lane -> row base + (lane&15), logical k-chunk lane>>4
    const int r    = lane & 15;
    const int pc   = ((lane >> 4) ^ ((r >> 1) & 3)) * 16;
    const int aoff = wm * 4096 + r * 64 + pc;           // + m*1024
    const int boff = 16384 + wn * 4096 + r * 64 + pc;   // + n*1024

    const int nt = K >> 6;

    STAGE(0, 0);
    STAGE(1, 64);

    v4i acc[4][4] = {};
    int cur = 0, nxt = 2;

    for (int t = 0; t < nt; ++t) {
        if (t < nt - 1) asm volatile("s_waitcnt vmcnt(3)" ::: "memory");
        else            asm volatile("s_waitcnt vmcnt(0)" ::: "memory");
        __builtin_amdgcn_s_barrier();   // buf[cur] globally ready; prev reads all done

        const signed char* L = &lds[cur][0];
        v4i af[4], bf[4];
        #pragma unroll
        for (int m = 0; m < 4; ++m) af[m] = *(const v4i*)(L + aoff + m * 1024);
        #pragma unroll
        for (int n = 0; n < 4; ++n) bf[n] = *(const v4i*)(L + boff + n * 1024);

        if (t + 2 < nt) STAGE(nxt, (t + 2) << 6);

        __builtin_amdgcn_s_setprio(1);
        #pragma unroll
        for (int m = 0; m < 4; ++m)
            #pragma unroll
            for (int n = 0; n < 4; ++n)
                acc[m][n] = __builtin_amdgcn_mfma_i32_16x16x64_i8(af[m], bf[n], acc[m][n], 0, 0, 0);
        __builtin_amdgcn_s_setprio(0);
        __builtin_amdgcn_s_barrier();

        cur = (cur == 2) ? 0 : cur + 1;
        nxt = (nxt == 2) ? 0 : nxt + 1;
    }
    #undef STAGE

    // ---- LDS-staged epilogue: C/D layout col = lane&15, row = (lane>>4)*4 + j ----
    const int rowb = wm * 64 + ((lane >> 4) << 2);
    const int colb = wn * 64 + (lane & 15);
    signed char* img0 = (signed char*)&lds[0][0];          // [256][136]
    signed char* img1 = img0 + 34816;

    if constexpr (EPI == 1) {
        const float Mv = Mscale[0];
        const float sv = qscale[0];
        #pragma unroll
        for (int n = 0; n < 4; ++n) {
            const int col  = colb + n * 16;
            const int bint = __float2int_rn(bias[bn0 + col]);
            #pragma unroll
            for (int m = 0; m < 4; ++m) {
                #pragma unroll
                for (int j = 0; j < 4; ++j) {
                    const int row  = rowb + m * 16 + j;
                    const int accv = acc[m][n][j] + bint;      // |acc1| <= 8.4M: f32-exact
                    float h = rintf(Mv * (float)accv);
                    h = fmaxf(h, 0.0f);
                    float q = rintf(h / sv);
                    q = fminf(fmaxf(q, -128.0f), 127.0f);
                    img0[row * 136 + col] = (signed char)(int)q;
                }
            }
        }
        __syncthreads();
        #pragma unroll
        for (int p = 0; p < 8; ++p) {
            const int idx = p * 512 + tid;
            const int row = idx >> 4;
            const int cb  = (idx & 15) * 8;
            *(int2*)(out0 + (size_t)(bm0 + row) * N + bn0 + cb) =
                *(const int2*)(img0 + row * 136 + cb);
        }
    } else {
        const float Mv = Mscale[0];
        #pragma unroll
        for (int n = 0; n < 4; ++n) {
            const int col  = colb + n * 16;
            const int bint = __float2int_rn(bias[bn0 + col]);
            #pragma unroll
            for (int m = 0; m < 4; ++m) {
                #pragma unroll
                for (int j = 0; j < 4; ++j) {
                    const int row  = rowb + m * 16 + j;
                    const int accv = acc[m][n][j] + bint;      // |acc2| <= 66.6M: f64 exact
                    double rr = rint((double)Mv * (double)accv);
                    rr = rr > 0.0 ? rr : 0.0;                  // relu; <= 65024
                    const int v = (int)rr;
                    img0[row * 136 + col] = (signed char)((v & 255) - 128);
                    img1[row * 136 + col] = (signed char)((v >> 8) - 128);
                }
            }
        }
        __syncthreads();
        #pragma unroll
        for (int p = 0; p < 8; ++p) {
            const int idx = p * 512 + tid;
            const int row = idx >> 4;
            const int cb  = (idx & 15) * 8;
            const size_t g = (size_t)(bm0 + row) * N + bn0 + cb;
            *(int2*)(out0 + g) = *(const int2*)(img0 + row * 136 + cb);
            *(int2*)(out1 + g) = *(const int2*)(img1 + row * 136 + cb);
        }
    }
}

// ---------------- head MFMA: partial[kblk][r][a] = 256*Phi + Plo over K-chunk 512 ----------------
__global__ __launch_bounds__(512, 1)
void head_mfma(const signed char* __restrict__ lo,
               const signed char* __restrict__ hi,
               const signed char* __restrict__ wpq,
               int* __restrict__ part)
{
    __shared__ __align__(16) signed char Bl[32768];       // 64 x 512 i8 (swizzled)
    __shared__ __align__(16) signed char Al[3][32768];    // [lo 256x64 | hi 256x64]

    const int tid  = threadIdx.x;
    const int lane = tid & 63;
    const int wid  = tid >> 6;
    const int rblk = blockIdx.x >> 3;
    const int kblk = blockIdx.x & 7;
    const int bm0  = rblk << 8;
    const int kb   = kblk << 9;

    // B preload (4 gload sets): phys (row = s*16 + tid>>5, chunk = tid&31), lc = chunk^(row&7)
    #pragma unroll
    for (int s = 0; s < 4; ++s) {
        const int brow = s * 16 + (tid >> 5);
        const int pch  = tid & 31;
        const int lc   = pch ^ (brow & 7);
        gload16(wpq + (size_t)brow * NH2 + kb + lc * 16, Bl + brow * 512 + pch * 16);
    }

    // A staging
    const int srow  = tid >> 2;
    const int sclog = (tid & 3) ^ ((tid >> 3) & 3);
    const size_t ab = (size_t)(bm0 + srow) * NH2 + kb + sclog * 16;
    const size_t rK = (size_t)128 * NH2;

    #define HSTAGE(bp, ko) do { \
        gload16(lo + ab + (ko),      &Al[bp][0]     + tid * 16); \
        gload16(lo + ab + rK + (ko), &Al[bp][8192]  + tid * 16); \
        gload16(hi + ab + (ko),      &Al[bp][16384] + tid * 16); \
        gload16(hi + ab + rK + (ko), &Al[bp][24576] + tid * 16); } while (0)

    HSTAGE(0, 0);
    HSTAGE(1, 64);

    const int r    = lane & 15;
    const int cg   = lane >> 4;
    const int pcA  = (cg ^ ((r >> 1) & 3)) * 16;
    const int aoff = wid * 2048 + r * 64 + pcA;   // wave rows wid*32; + m*1024

    v4i accL[2][4] = {}, accH[2][4] = {};
    int cur = 0, nxt = 2;

    for (int t = 0; t < 8; ++t) {
        if (t < 7) asm volatile("s_waitcnt vmcnt(4)" ::: "memory");
        else       asm volatile("s_waitcnt vmcnt(0)" ::: "memory");
        __builtin_amdgcn_s_barrier();

        const signed char* A = &Al[cur][0];
        v4i bf[4], al[2], ah[2];
        #pragma unroll
        for (int n = 0; n < 4; ++n)
            bf[n] = *(const v4i*)(Bl + (n * 16 + r) * 512 + (((t * 4 + cg) ^ (r & 7)) * 16));
        #pragma unroll
        for (int m = 0; m < 2; ++m) al[m] = *(const v4i*)(A + aoff + m * 1024);
        #pragma unroll
        for (int m = 0; m < 2; ++m) ah[m] = *(const v4i*)(A + 16384 + aoff + m * 1024);

        if (t + 2 < 8) HSTAGE(nxt, (t + 2) << 6);

        __builtin_amdgcn_s_setprio(1);
        #pragma unroll
        for (int m = 0; m < 2; ++m)
            #pragma unroll
            for (int n = 0; n < 4; ++n) {
                accL[m][n] = __builtin_amdgcn_mfma_i32_16x16x64_i8(al[m], bf[n], accL[m][n], 0, 0, 0);
                accH[m][n] = __builtin_amdgcn_mfma_i32_16x16x64_i8(ah[m], bf[n], accH[m][n], 0, 0, 0);
            }
        __builtin_amdgcn_s_setprio(0);
        __builtin_amdgcn_s_barrier();

        cur = (cur == 2) ? 0 : cur + 1;
        nxt = (nxt == 2) ? 0 : nxt + 1;
    }
    #undef HSTAGE

    int* pb = part + (size_t)kblk * (NB * NA);
    const int rowb = bm0 + wid * 32 + ((lane >> 4) << 2);
    #pragma unroll
    for (int m = 0; m < 2; ++m)
        #pragma unroll
        for (int n = 0; n < 4; ++n) {
            const int a = n * 16 + (lane & 15);
            #pragma unroll
            for (int j = 0; j < 4; ++j) {
                const int row = rowb + m * 16 + j;
                pb[(size_t)row * NA + a] = accL[m][n][j] + (accH[m][n][j] << 8);
            }
        }
}

// ---------------- combine: out = round(Mp*(sum parts + 32896*S[a] + b[a])) ----------------
__global__ __launch_bounds__(256)
void comb_head(const int* __restrict__ part, const int* __restrict__ S,
               const float* __restrict__ bp, const float* __restrict__ Mp,
               float* __restrict__ out)
{
    const int t = blockIdx.x * 256 + threadIdx.x;   // 524288
    const int a = t & 63;
    long long sum = 0;
    #pragma unroll
    for (int c = 0; c < 8; ++c) sum += part[(size_t)c * (NB * NA) + t];
    sum += 32896LL * (long long)S[a] + (long long)__float2int_rn(bp[a]);
    out[t] = (float)rint((double)Mp[0] * (double)sum);
}

// ---------------- launcher ----------------
extern "C" void kernel_launch(void* const* d_in, const int* in_sizes, int n_in,
                              void* d_out, int out_size, void* d_ws, size_t ws_size,
                              hipStream_t stream) {
    const float* x  = (const float*)d_in[0];
    const float* w1 = (const float*)d_in[1];
    const float* b1 = (const float*)d_in[2];
    const float* w2 = (const float*)d_in[3];
    const float* b2 = (const float*)d_in[4];
    const float* wp = (const float*)d_in[7];
    const float* bp = (const float*)d_in[8];
    const float* M1 = (const float*)d_in[9];
    const float* M2 = (const float*)d_in[10];
    const float* Mp = (const float*)d_in[12];
    const float* s2 = (const float*)d_in[13];

    const size_t MB = (size_t)1 << 20;
    char* ws = (char*)d_ws;
    signed char* x_i8  = (signed char*)(ws);              // 4 MiB   (dead after GEMM1)
    signed char* w1_i8 = (signed char*)(ws + 4  * MB);    // 2 MiB   (dead after GEMM1)
    signed char* w2_i8 = (signed char*)(ws + 6  * MB);    // 16 MiB  (dead after GEMM2)
    signed char* wp_i8 = (signed char*)(ws + 22 * MB);    // 256 KiB
    int*         Ssum  = (int*)        (ws + 22 * MB + 512 * 1024); // 256 B
    signed char* h1q   = (signed char*)(ws + 23 * MB);    // 32 MiB
    signed char* h2lo  = (signed char*)(ws + 55 * MB);    // 32 MiB
    signed char* h2hi  = (signed char*)(ws + 87 * MB);    // 32 MiB
    int*         part  = (int*)        (ws);              // 16 MiB, overlays x/w1/w2 (used only after GEMM2)

    cvt_i8<<<dim3(4096),  dim3(256), 0, stream>>>(x,  x_i8,  NB  * DIN / 4);
    cvt_i8<<<dim3(2048),  dim3(256), 0, stream>>>(w1, w1_i8, NH1 * DIN / 4);
    cvt_i8<<<dim3(16384), dim3(256), 0, stream>>>(w2, w2_i8, NH2 * NH1 / 4);
    cvt_i8<<<dim3(256),   dim3(256), 0, stream>>>(wp, wp_i8, NA  * NH2 / 4);
    sum_wp<<<dim3(64), dim3(256), 0, stream>>>(wp, Ssum);

    // GEMM1: (8192x512) x (4096x512)^T -> h1q int8
    gemm_i8_t3<1><<<dim3((NB / 256) * (NH1 / 128)), dim3(512), 0, stream>>>(
        x_i8, w1_i8, NB, NH1, DIN, b1, M1, s2, h1q, nullptr);
    // GEMM2: (8192x4096) x (4096x4096)^T -> h2lo/h2hi i8 planes
    gemm_i8_t3<2><<<dim3((NB / 256) * (NH2 / 128)), dim3(512), 0, stream>>>(
        h1q, w2_i8, NB, NH2, NH1, b2, M2, nullptr, h2lo, h2hi);
    // head: 256 blocks (32 row-tiles x 8 K-chunks) -> part, then combine
    head_mfma<<<dim3(256), dim3(512), 0, stream>>>(h2lo, h2hi, wp_i8, part);
    comb_head<<<dim3(NB * NA / 256), dim3(256), 0, stream>>>(part, Ssum, bp, Mp, (float*)d_out);
}

// Round 4
// 221.928 us; speedup vs baseline: 1.7044x; 1.0247x over previous
//
#include <hip/hip_runtime.h>
#include <stdint.h>

#define NB   8192
#define DIN  512
#define NH1  4096
#define NH2  4096
#define NA   64

typedef int v4i __attribute__((ext_vector_type(4)));

__device__ __forceinline__ v4i mfma_i8(v4i a, v4i b, v4i c) {
    return __builtin_amdgcn_mfma_i32_16x16x64_i8(a, b, c, 0, 0, 0);
}

// ---- async global->LDS, 16B per lane (dest = wave-uniform base + lane*16) ----
__device__ __forceinline__ void gload16(const void* g, const void* l) {
    __builtin_amdgcn_global_load_lds(
        (const __attribute__((address_space(1))) void*)(uintptr_t)g,
        (__attribute__((address_space(3))) void*)(uint32_t)(uintptr_t)l,
        16, 0, 0);
}

// ---------------- converts ----------------
__global__ void cvt_i8(const float* __restrict__ in, signed char* __restrict__ out, int n4) {
    const int i = blockIdx.x * blockDim.x + threadIdx.x;
    if (i >= n4) return;
    const float4 v = ((const float4*)in)[i];
    char4 c;
    c.x = (signed char)__float2int_rn(v.x);
    c.y = (signed char)__float2int_rn(v.y);
    c.z = (signed char)__float2int_rn(v.z);
    c.w = (signed char)__float2int_rn(v.w);
    ((char4*)out)[i] = c;
}

// S[a] = sum_k round(wp[a][k])
__global__ void sum_wp(const float* __restrict__ wp, int* __restrict__ S) {
    __shared__ int red[256];
    const int a = blockIdx.x, t = threadIdx.x;
    int p = 0;
    for (int k = t; k < NH2; k += 256) p += __float2int_rn(wp[(size_t)a * NH2 + k]);
    red[t] = p; __syncthreads();
    for (int s = 128; s > 0; s >>= 1) { if (t < s) red[t] += red[t + s]; __syncthreads(); }
    if (t == 0) S[a] = red[0];
}

// ---------------- i8 GEMM, C = A(MxK) * B(NxK)^T ----------------
// 256x256 tile, BK=128, 8 waves (2Mx4N), 2x64KB LDS buffers, 8-phase schedule,
// counted vmcnt(6) at phases 4/8 only, setprio around MFMA clusters.
// LDS buffer layout: A at 0, B at 32768; each: [half(2)][colhalf(2)][128 rows x 64B]
// with chunk XOR-swizzle: phys chunk = logical ^ ((row>>1)&3).
template <int EPI>
__global__ __launch_bounds__(512, 2)
void gemm_8ph(const signed char* __restrict__ Ag,
              const signed char* __restrict__ Bg,
              int M, int N, int K,
              const float* __restrict__ bias,
              const float* __restrict__ Mscale,
              const float* __restrict__ qscale,
              signed char* __restrict__ out0,
              signed char* __restrict__ out1)
{
    __shared__ __align__(16) signed char lds[2][65536];

    const int tid  = threadIdx.x;
    const int lane = tid & 63;
    const int wid  = tid >> 6;
    const int wm   = wid >> 2, wn = wid & 3;   // 2M x 4N waves; per-wave C: 128x64

    // XCD-aware bijective swizzle (grid divisible by 8)
    const int nwg  = gridDim.x;
    const int bid  = blockIdx.x;
    const int swzb = (bid & 7) * (nwg >> 3) + (bid >> 3);
    const int nbx  = N >> 8;
    const int bx   = swzb % nbx;
    const int by   = swzb / nbx;
    const int bm0  = by << 8, bn0 = bx << 8;

    // staging: thread t -> slab row t>>2, phys chunk t&3, logical chunk (t&3)^((t>>3)&3)
    const int srow = tid >> 2;
    const int sc   = (((tid & 3) ^ ((tid >> 3) & 3)) << 4);
    const signed char* aS = Ag + (size_t)(bm0 + srow) * K + sc;
    const signed char* bS = Bg + (size_t)(bn0 + srow) * K + sc;
    const size_t hK = (size_t)128 * K;
    const int NTm = (K >> 7) - 1;              // tile index mask (K/128 is pow2)

    // stage half-tile: buffer b, region isB, row-half h, K-tile t (2 gloads, colhalf 0/1)
#define STG(b, isB, h, t) do { \
    const signed char* s_ = ((isB) ? bS : aS) + (size_t)(h) * hK + (size_t)((t) & NTm) * 128; \
    signed char* d_ = &lds[b][0] + (isB) * 32768 + (h) * 16384 + tid * 16; \
    gload16(s_,      d_); \
    gload16(s_ + 64, d_ + 8192); } while (0)

    // ds_read base: lane -> frag row lane&15, logical k-chunk lane>>4, key (lane>>1)&3
    const int rp = (lane & 15) * 64 + ((((lane >> 4) ^ ((lane >> 1) & 3)) & 3) << 4);
    const int aB = wm * 4096 + rp;             // + (m>>2)*16384 + kh*8192 + (m&3)*1024
    const int bB = 32768 + wn * 1024 + rp;     // + (n>>1)*16384 + kh*8192 + (n&1)*4096

    // prologue: tile0 {A0,A1,B0,B1}, tile1 {A0,B0,B1}; wait tile0 (vmcnt(6) = 3 halves out)
    STG(0, 0, 0, 0); STG(0, 0, 1, 0); STG(0, 1, 0, 0); STG(0, 1, 1, 0);
    STG(1, 0, 0, 1); STG(1, 1, 0, 1); STG(1, 1, 1, 1);
    asm volatile("s_waitcnt vmcnt(6)" ::: "memory");
    asm volatile("s_barrier" ::: "memory");

    v4i acc[8][4] = {};

#define PHASE(mp, STG_STMT, WAIT_STMT) do { \
    v4i a00 = *(const v4i*)(L + ((2*(mp)) >> 2) * 16384 +        ((2*(mp)) & 3) * 1024 + aB); \
    v4i a01 = *(const v4i*)(L + ((2*(mp)) >> 2) * 16384 + 8192 + ((2*(mp)) & 3) * 1024 + aB); \
    v4i a10 = *(const v4i*)(L + ((2*(mp)+1) >> 2) * 16384 +        ((2*(mp)+1) & 3) * 1024 + aB); \
    v4i a11 = *(const v4i*)(L + ((2*(mp)+1) >> 2) * 16384 + 8192 + ((2*(mp)+1) & 3) * 1024 + aB); \
    STG_STMT; \
    WAIT_STMT; \
    asm volatile("s_barrier" ::: "memory"); \
    __builtin_amdgcn_s_setprio(1); \
    _Pragma("unroll") \
    for (int n = 0; n < 4; ++n) { \
        acc[2*(mp)][n]   = mfma_i8(a00, bf[n][0], acc[2*(mp)][n]); \
        acc[2*(mp)+1][n] = mfma_i8(a10, bf[n][0], acc[2*(mp)+1][n]); \
    } \
    _Pragma("unroll") \
    for (int n = 0; n < 4; ++n) { \
        acc[2*(mp)][n]   = mfma_i8(a01, bf[n][1], acc[2*(mp)][n]); \
        acc[2*(mp)+1][n] = mfma_i8(a11, bf[n][1], acc[2*(mp)+1][n]); \
    } \
    __builtin_amdgcn_s_setprio(0); \
    asm volatile("s_barrier" ::: "memory"); \
} while (0)

    // K-step on buffer BUF (4 phases). Phase 1 stages A1(TN) into OBUF;
    // phases 2-4 stage B0,B1,A0 of tile TN+1 into BUF. vmcnt(6) at phase 4.
#define KSTEP(BUF, OBUF, TN) do { \
    const signed char* L = &lds[BUF][0]; \
    v4i bf[4][2]; \
    _Pragma("unroll") \
    for (int n = 0; n < 4; ++n) { \
        bf[n][0] = *(const v4i*)(L + (n >> 1) * 16384 +        (n & 1) * 4096 + bB); \
        bf[n][1] = *(const v4i*)(L + (n >> 1) * 16384 + 8192 + (n & 1) * 4096 + bB); \
    } \
    PHASE(0, STG(OBUF, 0, 1, TN),     (void)0); \
    PHASE(1, STG(BUF,  1, 0, (TN)+1), (void)0); \
    PHASE(2, STG(BUF,  1, 1, (TN)+1), (void)0); \
    PHASE(3, STG(BUF,  0, 0, (TN)+1), asm volatile("s_waitcnt vmcnt(6)" ::: "memory")); \
} while (0)

    const int NI = (K >> 7) >> 1;
    for (int i = 0; i < NI; ++i) {
        const int t0 = 2 * i;
        KSTEP(0, 1, t0 + 1);   // compute tile t0   (buf0); stage A1(t0+1), {B0,B1,A0}(t0+2)
        KSTEP(1, 0, t0 + 2);   // compute tile t0+1 (buf1); stage A1(t0+2), {B0,B1,A0}(t0+3)
    }
#undef KSTEP
#undef PHASE
#undef STG

    // ---- epilogue: drain staging, reuse LDS as [256][264] byte image ----
    asm volatile("s_waitcnt vmcnt(0)" ::: "memory");
    __syncthreads();
    signed char* img = (signed char*)&lds[0][0];
    const int fr = (lane >> 4) << 2;   // fragment row group
    const int fc = lane & 15;          // fragment col

#define FLUSH(dst) do { \
    _Pragma("unroll") \
    for (int p = 0; p < 8; ++p) { \
        const int idx = p * 512 + tid; \
        const int row = idx >> 4, ch = (idx & 15) << 4; \
        *(int4*)((dst) + (size_t)(bm0 + row) * N + bn0 + ch) = *(const int4*)(img + row * 264 + ch); \
    } } while (0)

    if constexpr (EPI == 1) {
        const float Mv = Mscale[0];
        const float sv = qscale[0];
        #pragma unroll
        for (int n = 0; n < 4; ++n) {
            const int ecol = n * 64 + wn * 16 + fc;
            const int bint = __float2int_rn(bias[bn0 + ecol]);
            #pragma unroll
            for (int m = 0; m < 8; ++m) {
                const int erow = (m >> 2) * 128 + wm * 64 + (m & 3) * 16 + fr;
                #pragma unroll
                for (int j = 0; j < 4; ++j) {
                    const int accv = acc[m][n][j] + bint;      // |acc1| <= 8.4M: f32-exact
                    float h = rintf(Mv * (float)accv);
                    h = fmaxf(h, 0.0f);
                    float q = rintf(h / sv);
                    q = fminf(fmaxf(q, -128.0f), 127.0f);
                    img[(erow + j) * 264 + ecol] = (signed char)(int)q;
                }
            }
        }
        __syncthreads();
        FLUSH(out0);
    } else {
        const float Mv = Mscale[0];
        #pragma unroll
        for (int pass = 0; pass < 2; ++pass) {
            #pragma unroll
            for (int n = 0; n < 4; ++n) {
                const int ecol = n * 64 + wn * 16 + fc;
                const int bint = __float2int_rn(bias[bn0 + ecol]);
                #pragma unroll
                for (int m = 0; m < 8; ++m) {
                    const int erow = (m >> 2) * 128 + wm * 64 + (m & 3) * 16 + fr;
                    #pragma unroll
                    for (int j = 0; j < 4; ++j) {
                        const int accv = acc[m][n][j] + bint;  // |acc2| <= 66.6M: f64 exact
                        double rr = rint((double)Mv * (double)accv);
                        rr = rr > 0.0 ? rr : 0.0;              // relu; <= 65024
                        const int v = (int)rr;
                        const int byte = pass ? ((v >> 8) - 128) : ((v & 255) - 128);
                        img[(erow + j) * 264 + ecol] = (signed char)byte;
                    }
                }
            }
            __syncthreads();
            if (pass == 0) { FLUSH(out0); __syncthreads(); }
            else           { FLUSH(out1); }
        }
    }
#undef FLUSH
}

// ---------------- head MFMA: partial[kblk][r][a] = 256*Phi + Plo over K-chunk 512 ----------------
__global__ __launch_bounds__(512, 1)
void head_mfma(const signed char* __restrict__ lo,
               const signed char* __restrict__ hi,
               const signed char* __restrict__ wpq,
               int* __restrict__ part)
{
    __shared__ __align__(16) signed char Bl[32768];       // 64 x 512 i8 (swizzled)
    __shared__ __align__(16) signed char Al[3][32768];    // [lo 256x64 | hi 256x64]

    const int tid  = threadIdx.x;
    const int lane = tid & 63;
    const int wid  = tid >> 6;
    const int rblk = blockIdx.x >> 3;
    const int kblk = blockIdx.x & 7;
    const int bm0  = rblk << 8;
    const int kb   = kblk << 9;

    #pragma unroll
    for (int s = 0; s < 4; ++s) {
        const int brow = s * 16 + (tid >> 5);
        const int pch  = tid & 31;
        const int lc   = pch ^ (brow & 7);
        gload16(wpq + (size_t)brow * NH2 + kb + lc * 16, Bl + brow * 512 + pch * 16);
    }

    const int srow  = tid >> 2;
    const int sclog = (tid & 3) ^ ((tid >> 3) & 3);
    const size_t ab = (size_t)(bm0 + srow) * NH2 + kb + sclog * 16;
    const size_t rK = (size_t)128 * NH2;

    #define HSTAGE(bp, ko) do { \
        gload16(lo + ab + (ko),      &Al[bp][0]     + tid * 16); \
        gload16(lo + ab + rK + (ko), &Al[bp][8192]  + tid * 16); \
        gload16(hi + ab + (ko),      &Al[bp][16384] + tid * 16); \
        gload16(hi + ab + rK + (ko), &Al[bp][24576] + tid * 16); } while (0)

    HSTAGE(0, 0);
    HSTAGE(1, 64);

    const int r    = lane & 15;
    const int cg   = lane >> 4;
    const int pcA  = (cg ^ ((r >> 1) & 3)) * 16;
    const int aoff = wid * 2048 + r * 64 + pcA;

    v4i accL[2][4] = {}, accH[2][4] = {};
    int cur = 0, nxt = 2;

    for (int t = 0; t < 8; ++t) {
        if (t < 7) asm volatile("s_waitcnt vmcnt(4)" ::: "memory");
        else       asm volatile("s_waitcnt vmcnt(0)" ::: "memory");
        __builtin_amdgcn_s_barrier();

        const signed char* A = &Al[cur][0];
        v4i bf[4], al[2], ah[2];
        #pragma unroll
        for (int n = 0; n < 4; ++n)
            bf[n] = *(const v4i*)(Bl + (n * 16 + r) * 512 + (((t * 4 + cg) ^ (r & 7)) * 16));
        #pragma unroll
        for (int m = 0; m < 2; ++m) al[m] = *(const v4i*)(A + aoff + m * 1024);
        #pragma unroll
        for (int m = 0; m < 2; ++m) ah[m] = *(const v4i*)(A + 16384 + aoff + m * 1024);

        if (t + 2 < 8) HSTAGE(nxt, (t + 2) << 6);

        __builtin_amdgcn_s_setprio(1);
        #pragma unroll
        for (int m = 0; m < 2; ++m)
            #pragma unroll
            for (int n = 0; n < 4; ++n) {
                accL[m][n] = mfma_i8(al[m], bf[n], accL[m][n]);
                accH[m][n] = mfma_i8(ah[m], bf[n], accH[m][n]);
            }
        __builtin_amdgcn_s_setprio(0);
        __builtin_amdgcn_s_barrier();

        cur = (cur == 2) ? 0 : cur + 1;
        nxt = (nxt == 2) ? 0 : nxt + 1;
    }
    #undef HSTAGE

    int* pb = part + (size_t)kblk * (NB * NA);
    const int rowb = bm0 + wid * 32 + ((lane >> 4) << 2);
    #pragma unroll
    for (int m = 0; m < 2; ++m)
        #pragma unroll
        for (int n = 0; n < 4; ++n) {
            const int a = n * 16 + (lane & 15);
            #pragma unroll
            for (int j = 0; j < 4; ++j) {
                const int row = rowb + m * 16 + j;
                pb[(size_t)row * NA + a] = accL[m][n][j] + (accH[m][n][j] << 8);
            }
        }
}

// ---------------- combine: out = round(Mp*(sum parts + 32896*S[a] + b[a])) ----------------
__global__ __launch_bounds__(256)
void comb_head(const int* __restrict__ part, const int* __restrict__ S,
               const float* __restrict__ bp, const float* __restrict__ Mp,
               float* __restrict__ out)
{
    const int t = blockIdx.x * 256 + threadIdx.x;   // 524288
    const int a = t & 63;
    long long sum = 0;
    #pragma unroll
    for (int c = 0; c < 8; ++c) sum += part[(size_t)c * (NB * NA) + t];
    sum += 32896LL * (long long)S[a] + (long long)__float2int_rn(bp[a]);
    out[t] = (float)rint((double)Mp[0] * (double)sum);
}

// ---------------- launcher ----------------
extern "C" void kernel_launch(void* const* d_in, const int* in_sizes, int n_in,
                              void* d_out, int out_size, void* d_ws, size_t ws_size,
                              hipStream_t stream) {
    const float* x  = (const float*)d_in[0];
    const float* w1 = (const float*)d_in[1];
    const float* b1 = (const float*)d_in[2];
    const float* w2 = (const float*)d_in[3];
    const float* b2 = (const float*)d_in[4];
    const float* wp = (const float*)d_in[7];
    const float* bp = (const float*)d_in[8];
    const float* M1 = (const float*)d_in[9];
    const float* M2 = (const float*)d_in[10];
    const float* Mp = (const float*)d_in[12];
    const float* s2 = (const float*)d_in[13];

    const size_t MB = (size_t)1 << 20;
    char* ws = (char*)d_ws;
    signed char* x_i8  = (signed char*)(ws);              // 4 MiB   (dead after GEMM1)
    signed char* w1_i8 = (signed char*)(ws + 4  * MB);    // 2 MiB   (dead after GEMM1)
    signed char* w2_i8 = (signed char*)(ws + 6  * MB);    // 16 MiB  (dead after GEMM2)
    signed char* wp_i8 = (signed char*)(ws + 22 * MB);    // 256 KiB
    int*         Ssum  = (int*)        (ws + 22 * MB + 512 * 1024); // 256 B
    signed char* h1q   = (signed char*)(ws + 23 * MB);    // 32 MiB
    signed char* h2lo  = (signed char*)(ws + 55 * MB);    // 32 MiB
    signed char* h2hi  = (signed char*)(ws + 87 * MB);    // 32 MiB
    int*         part  = (int*)        (ws);              // 16 MiB, overlays x/w1/w2 (used only after GEMM2)

    cvt_i8<<<dim3(4096),  dim3(256), 0, stream>>>(x,  x_i8,  NB  * DIN / 4);
    cvt_i8<<<dim3(2048),  dim3(256), 0, stream>>>(w1, w1_i8, NH1 * DIN / 4);
    cvt_i8<<<dim3(16384), dim3(256), 0, stream>>>(w2, w2_i8, NH2 * NH1 / 4);
    cvt_i8<<<dim3(256),   dim3(256), 0, stream>>>(wp, wp_i8, NA  * NH2 / 4);
    sum_wp<<<dim3(64), dim3(256), 0, stream>>>(wp, Ssum);

    // GEMM1: (8192x512) x (4096x512)^T -> h1q int8
    gemm_8ph<1><<<dim3((NB / 256) * (NH1 / 256)), dim3(512), 0, stream>>>(
        x_i8, w1_i8, NB, NH1, DIN, b1, M1, s2, h1q, nullptr);
    // GEMM2: (8192x4096) x (4096x4096)^T -> h2lo/h2hi i8 planes
    gemm_8ph<2><<<dim3((NB / 256) * (NH2 / 256)), dim3(512), 0, stream>>>(
        h1q, w2_i8, NB, NH2, NH1, b2, M2, nullptr, h2lo, h2hi);
    // head: 256 blocks (32 row-tiles x 8 K-chunks) -> part, then combine
    head_mfma<<<dim3(256), dim3(512), 0, stream>>>(h2lo, h2hi, wp_i8, part);
    comb_head<<<dim3(NB * NA / 256), dim3(256), 0, stream>>>(part, Ssum, bp, Mp, (float*)d_out);
}